// Round 1
// baseline (391.259 us; speedup 1.0000x reference)
//
#include <hip/hip_runtime.h>
#include <hip/hip_bf16.h>

#define NPOS (384*384)
#define JDIM 384
#define CDIM 128
#define HNUM 4
#define DHD  32

#define LOG2E 1.4426950408889634f

typedef __attribute__((ext_vector_type(8))) short short8;
typedef __attribute__((ext_vector_type(4))) float floatx4;
typedef unsigned short ushort_t;

#if __has_builtin(__builtin_amdgcn_exp2f)
#define EXP2F(x) __builtin_amdgcn_exp2f(x)
#else
#define EXP2F(x) exp2f(x)
#endif

__device__ __forceinline__ float bf2f(unsigned short u){
  unsigned int x = ((unsigned int)u) << 16;
  return __builtin_bit_cast(float, x);
}
__device__ __forceinline__ unsigned short f2bf(float f){
  unsigned int u = __builtin_bit_cast(unsigned int, f);
  u = u + 0x7FFFu + ((u >> 16) & 1u);   // round-nearest-even
  return (unsigned short)(u >> 16);
}
// v_cvt_pk_bf16_f32: lo16 = bf16(a), hi16 = bf16(b), RNE (gfx950)
__device__ __forceinline__ unsigned int cvtpk_bf16(float a, float b){
  unsigned int r;
  asm("v_cvt_pk_bf16_f32 %0, %1, %2" : "=v"(r) : "v"(a), "v"(b));
  return r;
}

// ---------------- LayerNorm + triangle bias ----------------
// tri now stored TRANSPOSED per head: tri_t[h][k][q]  (k = j index, q = i index),
// pre-scaled by log2e so attn can use exp2 directly.
__global__ __launch_bounds__(256) void ln_tri_kernel(
    const float* __restrict__ x, const float* __restrict__ lnw,
    const float* __restrict__ lnb, const float* __restrict__ wtri,
    ushort_t* __restrict__ xn, float* __restrict__ trip)
{
  int wave = threadIdx.x >> 6, lane = threadIdx.x & 63;
  int pos = blockIdx.x * 4 + wave;
  const float2 xv = *(const float2*)(x + (size_t)pos*CDIM + lane*2);
  float x0 = xv.x, x1 = xv.y;
  float s = x0 + x1, ss = x0*x0 + x1*x1;
  #pragma unroll
  for (int o = 32; o > 0; o >>= 1){ s += __shfl_xor(s, o); ss += __shfl_xor(ss, o); }
  float mu  = s * (1.0f/128.0f);
  float var = ss * (1.0f/128.0f) - mu*mu;
  float rstd = rsqrtf(var + 1e-5f);
  float2 w2 = *(const float2*)(lnw + lane*2);
  float2 b2 = *(const float2*)(lnb + lane*2);
  float n0 = (x0 - mu)*rstd*w2.x + b2.x;
  float n1 = (x1 - mu)*rstd*w2.y + b2.y;
  ushort2 o2; o2.x = f2bf(n0); o2.y = f2bf(n1);
  *(ushort2*)(xn + (size_t)pos*CDIM + lane*2) = o2;
  float4 wt0 = *(const float4*)(wtri + lane*8);      // row c0 of [128,4]
  float4 wt1 = *(const float4*)(wtri + lane*8 + 4);  // row c1
  float t0 = n0*wt0.x + n1*wt1.x;
  float t1 = n0*wt0.y + n1*wt1.y;
  float t2 = n0*wt0.z + n1*wt1.z;
  float t3 = n0*wt0.w + n1*wt1.w;
  #pragma unroll
  for (int o = 32; o > 0; o >>= 1){
    t0 += __shfl_xor(t0, o); t1 += __shfl_xor(t1, o);
    t2 += __shfl_xor(t2, o); t3 += __shfl_xor(t3, o);
  }
  if (lane == 0){
    int i = pos / JDIM;
    int j = pos - i*JDIM;
    int tp = j*JDIM + i;               // transposed: [k=j][q=i]
    trip[0*NPOS + tp] = t0 * LOG2E;
    trip[1*NPOS + tp] = t1 * LOG2E;
    trip[2*NPOS + tp] = t2 * LOG2E;
    trip[3*NPOS + tp] = t3 * LOG2E;
  }
}

// ---------------- weight transpose + cast: W[c][f] fp32 -> Wt[f][c] bf16 ----------------
__global__ __launch_bounds__(256) void wt_kernel(
    const float* wq, const float* wk, const float* wv,
    const float* wg, const float* wo, ushort_t* __restrict__ wt)
{
  int mat = blockIdx.x >> 6;
  int idx = ((blockIdx.x & 63) << 8) | threadIdx.x;
  const float* src = (mat==0)?wq:(mat==1)?wk:(mat==2)?wv:(mat==3)?wg:wo;
  int f = idx >> 7, c = idx & 127;
  wt[mat*16384 + idx] = f2bf(src[c*128 + f]);
}

// ---------------- 128x128x128 MFMA GEMM tile ----------------
__device__ __forceinline__ void gemm_body(
    const ushort_t* __restrict__ A, const ushort_t* __restrict__ W,
    void* __restrict__ outv, const float* __restrict__ bias,
    int mode, int row0, ushort_t* As, ushort_t* Bs)
{
  int t = threadIdx.x;
  #pragma unroll
  for (int i = 0; i < 8; i++){
    int v = t + i*256;
    int row = v >> 4, c8 = v & 15;
    *(short8*)(As + row*144 + c8*8) = *(const short8*)(A + (size_t)(row0+row)*CDIM + c8*8);
    *(short8*)(Bs + row*144 + c8*8) = *(const short8*)(W + v*8);
  }
  __syncthreads();
  int w = t >> 6, lane = t & 63;
  int wm = (w & 1) * 64, wn = (w >> 1) * 64;
  int m = lane & 15, q4 = lane >> 4;
  floatx4 acc[4][4];
  #pragma unroll
  for (int mi = 0; mi < 4; mi++)
    #pragma unroll
    for (int ni = 0; ni < 4; ni++)
      acc[mi][ni] = (floatx4){0.f, 0.f, 0.f, 0.f};
  #pragma unroll
  for (int k0 = 0; k0 < 128; k0 += 32){
    int koff = k0 + q4*8;
    short8 af[4], bf[4];
    #pragma unroll
    for (int mi = 0; mi < 4; mi++) af[mi] = *(const short8*)(As + (wm + mi*16 + m)*144 + koff);
    #pragma unroll
    for (int ni = 0; ni < 4; ni++) bf[ni] = *(const short8*)(Bs + (wn + ni*16 + m)*144 + koff);
    #pragma unroll
    for (int mi = 0; mi < 4; mi++)
      #pragma unroll
      for (int ni = 0; ni < 4; ni++)
        acc[mi][ni] = __builtin_amdgcn_mfma_f32_16x16x32_bf16(af[mi], bf[ni], acc[mi][ni], 0, 0, 0);
  }
  // q scale folded with log2e so attention can use exp2 directly
  const float scale = 0.17677669529663687f * LOG2E;  // (1/sqrt(32)) * log2(e)
  #pragma unroll
  for (int mi = 0; mi < 4; mi++){
    #pragma unroll
    for (int ni = 0; ni < 4; ni++){
      int col = wn + ni*16 + m;
      float bv = (mode >= 2) ? bias[col] : 0.f;
      #pragma unroll
      for (int r = 0; r < 4; r++){
        float val = acc[mi][ni][r];
        if (mode == 1) val *= scale;
        else if (mode == 2) val = 1.f / (1.f + __expf(-(val + bv)));
        else if (mode == 3) val += bv;
        int row = wm + mi*16 + q4*4 + r;
        size_t oidx = (size_t)(row0+row)*CDIM + col;
        if (mode == 3) ((float*)outv)[oidx] = val;
        else           ((ushort_t*)outv)[oidx] = f2bf(val);
      }
    }
  }
}

__global__ __launch_bounds__(256) void proj_gemm_kernel(
    const ushort_t* __restrict__ xn, const ushort_t* __restrict__ wt,
    ushort_t* __restrict__ outb, const float* __restrict__ bg)
{
  __shared__ __align__(16) ushort_t As[128*144];
  __shared__ __align__(16) ushort_t Bs[128*144];
  int proj = blockIdx.y;                       // 0=q 1=k 2=v 3=g
  int mode = (proj == 0) ? 1 : (proj == 3) ? 2 : 0;
  gemm_body(xn, wt + proj*16384, outb + (size_t)proj*NPOS*CDIM, bg, mode,
            blockIdx.x * 128, As, Bs);
}

__global__ __launch_bounds__(256) void out_gemm_kernel(
    const ushort_t* __restrict__ og, const ushort_t* __restrict__ wt,
    float* __restrict__ out, const float* __restrict__ bo)
{
  __shared__ __align__(16) ushort_t As[128*144];
  __shared__ __align__(16) ushort_t Bs[128*144];
  gemm_body(og, wt, (void*)out, bo, 3, blockIdx.x * 128, As, Bs);
}

// ---------------- MFMA attention per (i,h) ----------------
// 512 threads = 8 waves; wave w owns Q-rows [w*48, w*48+48).  (was 4x96: now
// 4 waves/SIMD instead of 2 -> double latency hiding at identical LDS.)
// K [384][32] bf16 LDS; Vt [32][384] bf16 LDS (j-permuted, padded stride 392);
// P wave-private [48][32] bf16 (stride 40), same j-permutation.
// Triangle bias comes in TRANSPOSED [h][k][q], pre-scaled by log2e, and is
// folded (with the mask bias) into the MFMA accumulator init.
#define VT_STRIDE 392
#define P_STRIDE  40
__global__ __launch_bounds__(512, 4) void attn_kernel(
    const ushort_t* __restrict__ qb, const ushort_t* __restrict__ kb,
    const ushort_t* __restrict__ vb, const ushort_t* __restrict__ gb,
    const float* __restrict__ mask, const float* __restrict__ trip,
    ushort_t* __restrict__ og)
{
  __shared__ __align__(16) ushort_t Ks[JDIM*32];          // 24576 B
  __shared__ __align__(16) ushort_t Vt[32*VT_STRIDE];     // 25088 B
  __shared__ __align__(16) ushort_t Pb[8*48*P_STRIDE];    // 30720 B
  int i = blockIdx.x, h = blockIdx.y;
  int t = threadIdx.x;
  size_t rbase = (size_t)i * JDIM;

  // stage K natural, V transposed with within-block32 column permutation
  // actual col j = blk*32 + sub*16 + m  ->  stored pos blk*32 + m*2 + sub
  for (int idx = t; idx < JDIM*4; idx += 512){
    int j = idx >> 2, c8 = idx & 3;
    *(short8*)(Ks + j*32 + c8*8) = *(const short8*)(kb + (rbase + j)*CDIM + h*DHD + c8*8);
    short8 v8 = *(const short8*)(vb + (rbase + j)*CDIM + h*DHD + c8*8);
    int jb = j & 31;
    int jp = (j & ~31) | (((jb & 15) << 1) | (jb >> 4));
    #pragma unroll
    for (int e = 0; e < 8; e++) Vt[(c8*8 + e)*VT_STRIDE + jp] = (unsigned short)v8[e];
  }
  __syncthreads();

  int w = t >> 6, lane = t & 63;
  int m = lane & 15, q4 = lane >> 4;
  int wm = w * 48;
  ushort_t* Pw = Pb + w * 48 * P_STRIDE;

  // Q fragments (3 tiles of 16 rows), A-layout: lane m = row, k = q4*8..+8
  short8 qf[3];
  #pragma unroll
  for (int t6 = 0; t6 < 3; t6++)
    qf[t6] = *(const short8*)(qb + (rbase + wm + t6*16 + m)*CDIM + h*DHD + q4*8);

  floatx4 oacc[3][2];
  float lpart[3][4];
  #pragma unroll
  for (int t6 = 0; t6 < 3; t6++){
    oacc[t6][0] = (floatx4){0.f,0.f,0.f,0.f};
    oacc[t6][1] = (floatx4){0.f,0.f,0.f,0.f};
    #pragma unroll
    for (int r = 0; r < 4; r++) lpart[t6][r] = 0.f;
  }

  const float* triph = trip + (size_t)h * NPOS;   // transposed: [k][q]

  for (int kbk = 0; kbk < 12; kbk++){
    int col0 = kbk * 32;
    // B-fragments of K (lane m = key column)
    short8 kf0 = *(const short8*)(Ks + (col0 + m)*32 + q4*8);
    short8 kf1 = *(const short8*)(Ks + (col0 + 16 + m)*32 + q4*8);
    float mb0 = (1e9f*LOG2E) * (mask[rbase + col0 + m] - 1.0f);
    float mb1 = (1e9f*LOG2E) * (mask[rbase + col0 + 16 + m] - 1.0f);

    #pragma unroll
    for (int t6 = 0; t6 < 3; t6++){
      int qrow0 = wm + t6*16 + q4*4;
      // bias (tri*log2e + mask*log2e) folded into MFMA C-init
      float4 tt0 = *(const float4*)(triph + (size_t)(col0 + m)*JDIM + qrow0);
      float4 tt1 = *(const float4*)(triph + (size_t)(col0 + 16 + m)*JDIM + qrow0);
      floatx4 z0 = (floatx4){tt0.x + mb0, tt0.y + mb0, tt0.z + mb0, tt0.w + mb0};
      floatx4 z1 = (floatx4){tt1.x + mb1, tt1.y + mb1, tt1.z + mb1, tt1.w + mb1};
      floatx4 s0 = __builtin_amdgcn_mfma_f32_16x16x32_bf16(qf[t6], kf0, z0, 0, 0, 0);
      floatx4 s1 = __builtin_amdgcn_mfma_f32_16x16x32_bf16(qf[t6], kf1, z1, 0, 0, 0);
      #pragma unroll
      for (int r = 0; r < 4; r++){
        float p0 = EXP2F(s0[r]);
        float p1 = EXP2F(s1[r]);
        lpart[t6][r] += p0 + p1;
        // store cols (m, m+16) packed at permuted pos m*2, m*2+1
        *(unsigned int*)(Pw + (t6*16 + q4*4 + r)*P_STRIDE + m*2) = cvtpk_bf16(p0, p1);
      }
    }
    // PV: A = P (permuted k), B = Vt (same permutation)
    short8 vf0 = *(const short8*)(Vt + m*VT_STRIDE + col0 + q4*8);
    short8 vf1 = *(const short8*)(Vt + (16 + m)*VT_STRIDE + col0 + q4*8);
    #pragma unroll
    for (int t6 = 0; t6 < 3; t6++){
      short8 pf = *(const short8*)(Pw + (t6*16 + m)*P_STRIDE + q4*8);
      oacc[t6][0] = __builtin_amdgcn_mfma_f32_16x16x32_bf16(pf, vf0, oacc[t6][0], 0, 0, 0);
      oacc[t6][1] = __builtin_amdgcn_mfma_f32_16x16x32_bf16(pf, vf1, oacc[t6][1], 0, 0, 0);
    }
  }

  // reduce l across the 16 m-lanes (same q4 group holds same rows)
  #pragma unroll
  for (int t6 = 0; t6 < 3; t6++)
    #pragma unroll
    for (int r = 0; r < 4; r++){
      float l = lpart[t6][r];
      l += __shfl_xor(l, 1); l += __shfl_xor(l, 2);
      l += __shfl_xor(l, 4); l += __shfl_xor(l, 8);
      lpart[t6][r] = 1.0f / (l + 1e-30f);
    }

  // epilogue: o = acc * (1/l) * g
  #pragma unroll
  for (int t6 = 0; t6 < 3; t6++){
    int qrow = wm + t6*16 + q4*4;
    #pragma unroll
    for (int dt = 0; dt < 2; dt++){
      #pragma unroll
      for (int r = 0; r < 4; r++){
        size_t oidx = (rbase + qrow + r)*CDIM + h*DHD + dt*16 + m;
        float o = oacc[t6][dt][r] * lpart[t6][r] * bf2f(gb[oidx]);
        og[oidx] = f2bf(o);
      }
    }
  }
}

extern "C" void kernel_launch(void* const* d_in, const int* in_sizes, int n_in,
                              void* d_out, int out_size, void* d_ws, size_t ws_size,
                              hipStream_t stream)
{
  const float* x    = (const float*)d_in[0];
  const float* mask = (const float*)d_in[1];
  const float* lnw  = (const float*)d_in[2];
  const float* lnb  = (const float*)d_in[3];
  const float* wtri = (const float*)d_in[4];
  const float* wq   = (const float*)d_in[5];
  const float* wk   = (const float*)d_in[6];
  const float* wv   = (const float*)d_in[7];
  const float* wg   = (const float*)d_in[8];
  const float* bg   = (const float*)d_in[9];
  const float* wo   = (const float*)d_in[10];
  const float* bo   = (const float*)d_in[11];

  char* ws = (char*)d_ws;
  const size_t SZ = (size_t)NPOS * CDIM * 2;     // 37,748,736 B per [N,128] bf16
  ushort_t* xn  = (ushort_t*)(ws);
  ushort_t* qb  = (ushort_t*)(ws + 1*SZ);
  ushort_t* kbp = (ushort_t*)(ws + 2*SZ);
  ushort_t* vbp = (ushort_t*)(ws + 3*SZ);
  ushort_t* gbp = (ushort_t*)(ws + 4*SZ);
  ushort_t* og  = (ushort_t*)(ws + 5*SZ);
  ushort_t* wt  = (ushort_t*)(ws + 6*SZ);        // 5 * 128*128 bf16
  float*    tri = (float*)(ws + 6*SZ + 5*16384*2);

  ln_tri_kernel<<<NPOS/4, 256, 0, stream>>>(x, lnw, lnb, wtri, xn, tri);
  wt_kernel<<<320, 256, 0, stream>>>(wq, wk, wv, wg, wo, wt);
  proj_gemm_kernel<<<dim3(NPOS/128, 4), 256, 0, stream>>>(xn, wt, qb, bg);
  attn_kernel<<<dim3(JDIM, HNUM), 512, 0, stream>>>(qb, kbp, vbp, gbp, mask, tri, og);
  out_gemm_kernel<<<NPOS/128, 256, 0, stream>>>(og, wt + 4*16384, (float*)d_out, bo);
}

// Round 2
// 338.193 us; speedup vs baseline: 1.1569x; 1.1569x over previous
//
#include <hip/hip_runtime.h>
#include <hip/hip_bf16.h>

#define NPOS (384*384)
#define JDIM 384
#define CDIM 128
#define HNUM 4
#define DHD  32

#define LOG2E 1.4426950408889634f

typedef __attribute__((ext_vector_type(8))) short short8;
typedef __attribute__((ext_vector_type(4))) float floatx4;
typedef __attribute__((ext_vector_type(4))) unsigned int uintx4;
typedef unsigned short ushort_t;

#if __has_builtin(__builtin_amdgcn_exp2f)
#define EXP2F(x) __builtin_amdgcn_exp2f(x)
#else
#define EXP2F(x) exp2f(x)
#endif

__device__ __forceinline__ float bf2f(unsigned short u){
  unsigned int x = ((unsigned int)u) << 16;
  return __builtin_bit_cast(float, x);
}
__device__ __forceinline__ unsigned short f2bf(float f){
  unsigned int u = __builtin_bit_cast(unsigned int, f);
  u = u + 0x7FFFu + ((u >> 16) & 1u);   // round-nearest-even
  return (unsigned short)(u >> 16);
}
// v_cvt_pk_bf16_f32: lo16 = bf16(a), hi16 = bf16(b), RNE (gfx950)
__device__ __forceinline__ unsigned int cvtpk_bf16(float a, float b){
  unsigned int r;
  asm("v_cvt_pk_bf16_f32 %0, %1, %2" : "=v"(r) : "v"(a), "v"(b));
  return r;
}

// ---------------- LayerNorm + triangle bias ----------------
// tri stored per head as tri_p[h][kk>>2][q][kk&3]  (kk = key j, q = query i),
// pre-scaled by log2e, so attn loads one float4 per (lane, 4 kk) fully coalesced
// and folds it straight into the MFMA C-init.
__global__ __launch_bounds__(256) void ln_tri_kernel(
    const float* __restrict__ x, const float* __restrict__ lnw,
    const float* __restrict__ lnb, const float* __restrict__ wtri,
    ushort_t* __restrict__ xn, float* __restrict__ trip)
{
  int wave = threadIdx.x >> 6, lane = threadIdx.x & 63;
  int pos = blockIdx.x * 4 + wave;
  const float2 xv = *(const float2*)(x + (size_t)pos*CDIM + lane*2);
  float x0 = xv.x, x1 = xv.y;
  float s = x0 + x1, ss = x0*x0 + x1*x1;
  #pragma unroll
  for (int o = 32; o > 0; o >>= 1){ s += __shfl_xor(s, o); ss += __shfl_xor(ss, o); }
  float mu  = s * (1.0f/128.0f);
  float var = ss * (1.0f/128.0f) - mu*mu;
  float rstd = rsqrtf(var + 1e-5f);
  float2 w2 = *(const float2*)(lnw + lane*2);
  float2 b2 = *(const float2*)(lnb + lane*2);
  float n0 = (x0 - mu)*rstd*w2.x + b2.x;
  float n1 = (x1 - mu)*rstd*w2.y + b2.y;
  ushort2 o2; o2.x = f2bf(n0); o2.y = f2bf(n1);
  *(ushort2*)(xn + (size_t)pos*CDIM + lane*2) = o2;
  float4 wt0 = *(const float4*)(wtri + lane*8);      // row c0 of [128,4]
  float4 wt1 = *(const float4*)(wtri + lane*8 + 4);  // row c1
  float t0 = n0*wt0.x + n1*wt1.x;
  float t1 = n0*wt0.y + n1*wt1.y;
  float t2 = n0*wt0.z + n1*wt1.z;
  float t3 = n0*wt0.w + n1*wt1.w;
  #pragma unroll
  for (int o = 32; o > 0; o >>= 1){
    t0 += __shfl_xor(t0, o); t1 += __shfl_xor(t1, o);
    t2 += __shfl_xor(t2, o); t3 += __shfl_xor(t3, o);
  }
  if (lane == 0){
    int i = pos / JDIM;        // q index
    int j = pos - i*JDIM;      // kk index
    int tp = (j >> 2)*(JDIM*4) + i*4 + (j & 3);
    trip[0*NPOS + tp] = t0 * LOG2E;
    trip[1*NPOS + tp] = t1 * LOG2E;
    trip[2*NPOS + tp] = t2 * LOG2E;
    trip[3*NPOS + tp] = t3 * LOG2E;
  }
}

// ---------------- weight transpose + cast: W[c][f] fp32 -> Wt[f][c] bf16 ----------------
__global__ __launch_bounds__(256) void wt_kernel(
    const float* wq, const float* wk, const float* wv,
    const float* wg, const float* wo, ushort_t* __restrict__ wt)
{
  int mat = blockIdx.x >> 6;
  int idx = ((blockIdx.x & 63) << 8) | threadIdx.x;
  const float* src = (mat==0)?wq:(mat==1)?wk:(mat==2)?wv:(mat==3)?wg:wo;
  int f = idx >> 7, c = idx & 127;
  wt[mat*16384 + idx] = f2bf(src[c*128 + f]);
}

// ---------------- 128x128x128 MFMA GEMM tile ----------------
__device__ __forceinline__ void gemm_body(
    const ushort_t* __restrict__ A, const ushort_t* __restrict__ W,
    void* __restrict__ outv, const float* __restrict__ bias,
    int mode, int row0, ushort_t* As, ushort_t* Bs)
{
  int t = threadIdx.x;
  #pragma unroll
  for (int i = 0; i < 8; i++){
    int v = t + i*256;
    int row = v >> 4, c8 = v & 15;
    *(short8*)(As + row*144 + c8*8) = *(const short8*)(A + (size_t)(row0+row)*CDIM + c8*8);
    *(short8*)(Bs + row*144 + c8*8) = *(const short8*)(W + v*8);
  }
  __syncthreads();
  int w = t >> 6, lane = t & 63;
  int wm = (w & 1) * 64, wn = (w >> 1) * 64;
  int m = lane & 15, q4 = lane >> 4;
  floatx4 acc[4][4];
  #pragma unroll
  for (int mi = 0; mi < 4; mi++)
    #pragma unroll
    for (int ni = 0; ni < 4; ni++)
      acc[mi][ni] = (floatx4){0.f, 0.f, 0.f, 0.f};
  #pragma unroll
  for (int k0 = 0; k0 < 128; k0 += 32){
    int koff = k0 + q4*8;
    short8 af[4], bf[4];
    #pragma unroll
    for (int mi = 0; mi < 4; mi++) af[mi] = *(const short8*)(As + (wm + mi*16 + m)*144 + koff);
    #pragma unroll
    for (int ni = 0; ni < 4; ni++) bf[ni] = *(const short8*)(Bs + (wn + ni*16 + m)*144 + koff);
    #pragma unroll
    for (int mi = 0; mi < 4; mi++)
      #pragma unroll
      for (int ni = 0; ni < 4; ni++)
        acc[mi][ni] = __builtin_amdgcn_mfma_f32_16x16x32_bf16(af[mi], bf[ni], acc[mi][ni], 0, 0, 0);
  }
  // q scale folded with log2e so attention can use exp2 directly
  const float scale = 0.17677669529663687f * LOG2E;  // (1/sqrt(32)) * log2(e)
  #pragma unroll
  for (int mi = 0; mi < 4; mi++){
    #pragma unroll
    for (int ni = 0; ni < 4; ni++){
      int col = wn + ni*16 + m;
      float bv = (mode >= 2) ? bias[col] : 0.f;
      #pragma unroll
      for (int r = 0; r < 4; r++){
        float val = acc[mi][ni][r];
        if (mode == 1) val *= scale;
        else if (mode == 2) val = 1.f / (1.f + __expf(-(val + bv)));
        else if (mode == 3) val += bv;
        int row = wm + mi*16 + q4*4 + r;
        size_t oidx = (size_t)(row0+row)*CDIM + col;
        if (mode == 3) ((float*)outv)[oidx] = val;
        else           ((ushort_t*)outv)[oidx] = f2bf(val);
      }
    }
  }
}

__global__ __launch_bounds__(256) void proj_gemm_kernel(
    const ushort_t* __restrict__ xn, const ushort_t* __restrict__ wt,
    ushort_t* __restrict__ outb, const float* __restrict__ bg)
{
  __shared__ __align__(16) ushort_t As[128*144];
  __shared__ __align__(16) ushort_t Bs[128*144];
  int proj = blockIdx.y;                       // 0=q 1=k 2=v 3=g
  int mode = (proj == 0) ? 1 : (proj == 3) ? 2 : 0;
  gemm_body(xn, wt + proj*16384, outb + (size_t)proj*NPOS*CDIM, bg, mode,
            blockIdx.x * 128, As, Bs);
}

__global__ __launch_bounds__(256) void out_gemm_kernel(
    const ushort_t* __restrict__ og, const ushort_t* __restrict__ wt,
    float* __restrict__ out, const float* __restrict__ bo)
{
  __shared__ __align__(16) ushort_t As[128*144];
  __shared__ __align__(16) ushort_t Bs[128*144];
  gemm_body(og, wt, (void*)out, bo, 3, blockIdx.x * 128, As, Bs);
}

// ---------------- MFMA attention per (i,h) ----------------
// 512 threads = 8 waves; wave w owns Q-rows [w*48, w*48+48).
// SWAPPED QK: s = mfma(K, Q) -> D[kk][q], lane = q, regs = kk.  Each lane then
// holds 8 P-values whose kk indices are a fixed permutation of the 32-k block;
// Vt is stored with exactly that column permutation, so P feeds the PV MFMA's
// A-fragment DIRECTLY FROM REGISTERS (no P LDS buffer, no lgkm round trip).
//   perm: kp (stored) -> actual k = (kp&4?16:0) + (kp>>3)*4 + (kp&3)
//   inverse: k -> kp = ((k>>2)&3)*8 + ((k>>4)<<2) + (k&3)
// K [384][36-padded] bf16 LDS (stride 36 shorts kills the 8-way bank conflict
// of the old stride-32 ds_read_b128); Vt [32][392] bf16 LDS.
// LDS total 52.7 KB -> 3 blocks/CU (24 waves, was 2 blocks/16 waves).
#define KS_STRIDE 36
#define VT_STRIDE 392
__global__ __launch_bounds__(512, 4) void attn_kernel(
    const ushort_t* __restrict__ qb, const ushort_t* __restrict__ kb,
    const ushort_t* __restrict__ vb, const ushort_t* __restrict__ gb,
    const float* __restrict__ mask, const float* __restrict__ trip,
    ushort_t* __restrict__ og)
{
  __shared__ __align__(16) ushort_t Ks[JDIM*KS_STRIDE];   // 27648 B
  __shared__ __align__(16) ushort_t Vt[32*VT_STRIDE];     // 25088 B
  int i = blockIdx.x, h = blockIdx.y;
  int t = threadIdx.x;
  size_t rbase = (size_t)i * JDIM;

  // stage K natural (padded), V transposed with the PV register permutation
  for (int idx = t; idx < JDIM*4; idx += 512){
    int j = idx >> 2, c8 = idx & 3;
    *(short8*)(Ks + j*KS_STRIDE + c8*8) = *(const short8*)(kb + (rbase + j)*CDIM + h*DHD + c8*8);
    short8 v8 = *(const short8*)(vb + (rbase + j)*CDIM + h*DHD + c8*8);
    int jb = j & 31;
    int jp = (j & ~31) | (((jb >> 2) & 3)*8 + ((jb >> 4) << 2) + (jb & 3));
    #pragma unroll
    for (int e = 0; e < 8; e++) Vt[(c8*8 + e)*VT_STRIDE + jp] = (unsigned short)v8[e];
  }
  __syncthreads();

  int w = t >> 6, lane = t & 63;
  int m = lane & 15, q4 = lane >> 4;
  int wm = w * 48;

  // Q fragments (3 tiles of 16 rows), B-fragment: lane m = q-row, k = q4*8..+8
  short8 qf[3];
  #pragma unroll
  for (int t6 = 0; t6 < 3; t6++)
    qf[t6] = *(const short8*)(qb + (rbase + wm + t6*16 + m)*CDIM + h*DHD + q4*8);

  floatx4 oacc[3][2];
  float lsum[3];
  #pragma unroll
  for (int t6 = 0; t6 < 3; t6++){
    oacc[t6][0] = (floatx4){0.f,0.f,0.f,0.f};
    oacc[t6][1] = (floatx4){0.f,0.f,0.f,0.f};
    lsum[t6] = 0.f;
  }

  const float* triph = trip + (size_t)h * NPOS;   // [kk>>2][q][kk&3]
  const float MC = 1e9f * LOG2E;

  for (int kbk = 0; kbk < 12; kbk++){
    int col0 = kbk * 32;
    // A-fragments of K (lane m = key row kk)
    short8 kf0 = *(const short8*)(Ks + (col0 + m)*KS_STRIDE + q4*8);
    short8 kf1 = *(const short8*)(Ks + (col0 + 16 + m)*KS_STRIDE + q4*8);
    // mask bias: kk = col0 + q4*4 + r (+16), uniform across lanes m
    float4 mk0 = *(const float4*)(mask + rbase + col0 + q4*4);
    float4 mk1 = *(const float4*)(mask + rbase + col0 + 16 + q4*4);
    float mb0[4] = {(mk0.x-1.f)*MC, (mk0.y-1.f)*MC, (mk0.z-1.f)*MC, (mk0.w-1.f)*MC};
    float mb1[4] = {(mk1.x-1.f)*MC, (mk1.y-1.f)*MC, (mk1.z-1.f)*MC, (mk1.w-1.f)*MC};
    // B-fragments of V (lane m = d col, elements = permuted kk)
    short8 vf0 = *(const short8*)(Vt + m*VT_STRIDE + col0 + q4*8);
    short8 vf1 = *(const short8*)(Vt + (16 + m)*VT_STRIDE + col0 + q4*8);

    const float* tb0 = triph + (size_t)(kbk*8 + q4)*(JDIM*4);
    const float* tb1 = triph + (size_t)(kbk*8 + 4 + q4)*(JDIM*4);

    #pragma unroll
    for (int t6 = 0; t6 < 3; t6++){
      int q0t = wm + t6*16;
      // tri bias (already *log2e) for 4 kk (r dim) at q = q0t+m, one float4
      float4 tt0 = *(const float4*)(tb0 + (q0t + m)*4);
      float4 tt1 = *(const float4*)(tb1 + (q0t + m)*4);
      floatx4 z0 = (floatx4){tt0.x + mb0[0], tt0.y + mb0[1], tt0.z + mb0[2], tt0.w + mb0[3]};
      floatx4 z1 = (floatx4){tt1.x + mb1[0], tt1.y + mb1[1], tt1.z + mb1[2], tt1.w + mb1[3]};
      floatx4 s0 = __builtin_amdgcn_mfma_f32_16x16x32_bf16(kf0, qf[t6], z0, 0, 0, 0);
      floatx4 s1 = __builtin_amdgcn_mfma_f32_16x16x32_bf16(kf1, qf[t6], z1, 0, 0, 0);
      float p0 = EXP2F(s0[0]), p1 = EXP2F(s0[1]), p2 = EXP2F(s0[2]), p3 = EXP2F(s0[3]);
      float p4 = EXP2F(s1[0]), p5 = EXP2F(s1[1]), p6 = EXP2F(s1[2]), p7 = EXP2F(s1[3]);
      lsum[t6] += ((p0 + p1) + (p2 + p3)) + ((p4 + p5) + (p6 + p7));
      uintx4 pk = (uintx4){cvtpk_bf16(p0, p1), cvtpk_bf16(p2, p3),
                           cvtpk_bf16(p4, p5), cvtpk_bf16(p6, p7)};
      short8 pf = __builtin_bit_cast(short8, pk);
      oacc[t6][0] = __builtin_amdgcn_mfma_f32_16x16x32_bf16(pf, vf0, oacc[t6][0], 0, 0, 0);
      oacc[t6][1] = __builtin_amdgcn_mfma_f32_16x16x32_bf16(pf, vf1, oacc[t6][1], 0, 0, 0);
    }
  }

  // l(q): lane holds partial for q = tile + m; reduce across the 4 q4 groups
  float lrec[3];
  #pragma unroll
  for (int t6 = 0; t6 < 3; t6++){
    float l = lsum[t6];
    l += __shfl_xor(l, 16);
    l += __shfl_xor(l, 32);
    lrec[t6] = 1.0f / (l + 1e-30f);
  }

  // epilogue: o = acc * (1/l) * g.  O layout: lane m = d col, q = q4*4+r;
  // l for row q4*4+r lives at lane (q4*4+r) -> shfl broadcast.
  #pragma unroll
  for (int t6 = 0; t6 < 3; t6++){
    #pragma unroll
    for (int r = 0; r < 4; r++){
      float lrq = __shfl(lrec[t6], (q4 << 2) + r);
      int qrow = wm + t6*16 + q4*4 + r;
      #pragma unroll
      for (int dt = 0; dt < 2; dt++){
        size_t oidx = (rbase + qrow)*CDIM + h*DHD + dt*16 + m;
        float o = oacc[t6][dt][r] * lrq * bf2f(gb[oidx]);
        og[oidx] = f2bf(o);
      }
    }
  }
}

extern "C" void kernel_launch(void* const* d_in, const int* in_sizes, int n_in,
                              void* d_out, int out_size, void* d_ws, size_t ws_size,
                              hipStream_t stream)
{
  const float* x    = (const float*)d_in[0];
  const float* mask = (const float*)d_in[1];
  const float* lnw  = (const float*)d_in[2];
  const float* lnb  = (const float*)d_in[3];
  const float* wtri = (const float*)d_in[4];
  const float* wq   = (const float*)d_in[5];
  const float* wk   = (const float*)d_in[6];
  const float* wv   = (const float*)d_in[7];
  const float* wg   = (const float*)d_in[8];
  const float* bg   = (const float*)d_in[9];
  const float* wo   = (const float*)d_in[10];
  const float* bo   = (const float*)d_in[11];

  char* ws = (char*)d_ws;
  const size_t SZ = (size_t)NPOS * CDIM * 2;     // 37,748,736 B per [N,128] bf16
  ushort_t* xn  = (ushort_t*)(ws);
  ushort_t* qb  = (ushort_t*)(ws + 1*SZ);
  ushort_t* kbp = (ushort_t*)(ws + 2*SZ);
  ushort_t* vbp = (ushort_t*)(ws + 3*SZ);
  ushort_t* gbp = (ushort_t*)(ws + 4*SZ);
  ushort_t* og  = (ushort_t*)(ws + 5*SZ);
  ushort_t* wt  = (ushort_t*)(ws + 6*SZ);        // 5 * 128*128 bf16
  float*    tri = (float*)(ws + 6*SZ + 5*16384*2);

  ln_tri_kernel<<<NPOS/4, 256, 0, stream>>>(x, lnw, lnb, wtri, xn, tri);
  wt_kernel<<<320, 256, 0, stream>>>(wq, wk, wv, wg, wo, wt);
  proj_gemm_kernel<<<dim3(NPOS/128, 4), 256, 0, stream>>>(xn, wt, qb, bg);
  attn_kernel<<<dim3(JDIM, HNUM), 512, 0, stream>>>(qb, kbp, vbp, gbp, mask, tri, og);
  out_gemm_kernel<<<NPOS/128, 256, 0, stream>>>(og, wt + 4*16384, (float*)d_out, bo);
}